// Round 3
// baseline (26.242 us; speedup 1.0000x reference)
//
#include <hip/hip_runtime.h>

#define BATCH 4
#define N_CH 3
#define NUM_CLASSES 20
#define IMG_H 512
#define IMG_W 512
#define MAX_BOXES 50
#define NSLOTS (BATCH * MAX_BOXES)
#define PARTS 64            // row-stripe parts per box
#define RPP 4               // rows per part  (PARTS*RPP = 256 >= max box height)

// One (box, 4-row stripe) per 64-thread block. Lanes stride across columns.
// All 24 loads of a column-iteration (4 rows x 3 ch x 2 tensors) are unrolled
// so they issue before the first wait -> ~1 HBM latency per column-iteration.
// Raw sum atomicAdd'ed into ws[slot] (<=64-way contention, 200 parallel addrs).
__global__ __launch_bounds__(64)
void box_err_kernel(const float* __restrict__ y_fcn,
                    const float* __restrict__ im_data,
                    const int*   __restrict__ gt_boxes,
                    const int*   __restrict__ num_boxes,
                    float*       __restrict__ ws_acc) {
    const int slot = blockIdx.x >> 6;         // / PARTS
    const int part = blockIdx.x & (PARTS - 1);
    const int b    = slot / MAX_BOXES;
    const int box  = slot % MAX_BOXES;

    if (box >= num_boxes[b]) return;

    const int* g  = gt_boxes + slot * 5;
    const int x1 = g[0], y1 = g[1], x2 = g[2], y2 = g[3], cls = g[4];
    const int bw = x2 - x1;
    const int bh = y2 - y1;

    const int r0 = part * RPP;
    if (r0 >= bh) return;
    const int nr = min(RPP, bh - r0);

    const size_t plane = (size_t)IMG_H * IMG_W;
    const float* im = im_data + (size_t)b * N_CH * plane;
    const float* yf = y_fcn + ((size_t)b * NUM_CLASSES + cls) * N_CH * plane;

    const int rowbase = (y1 + r0) * IMG_W + x1;

    float s = 0.0f;
    if (nr == RPP) {                           // full stripe: deep unroll, max MLP
        for (int c = (int)threadIdx.x; c < bw; c += 64) {
            const int off = rowbase + c;
            #pragma unroll
            for (int r = 0; r < RPP; ++r) {
                #pragma unroll
                for (int nn = 0; nn < N_CH; ++nn) {
                    const int o = nn * (int)plane + off + r * IMG_W;
                    const float d = im[o] - yf[o];
                    s = fmaf(d, d, s);
                }
            }
        }
    } else {                                   // edge stripe (uniform branch)
        for (int c = (int)threadIdx.x; c < bw; c += 64) {
            const int off = rowbase + c;
            for (int r = 0; r < nr; ++r) {
                #pragma unroll
                for (int nn = 0; nn < N_CH; ++nn) {
                    const int o = nn * (int)plane + off + r * IMG_W;
                    const float d = im[o] - yf[o];
                    s = fmaf(d, d, s);
                }
            }
        }
    }

    #pragma unroll
    for (int off = 32; off > 0; off >>= 1)
        s += __shfl_down(s, off, 64);

    if (threadIdx.x == 0 && s != 0.0f)
        atomicAdd(&ws_acc[slot], s);
}

// Single block: err[slot] = ws[slot] / (N_CH * area); out = sum(err) / sum(num_boxes)
__global__ __launch_bounds__(256)
void finalize_kernel(const float* __restrict__ ws_acc,
                     const int*   __restrict__ gt_boxes,
                     const int*   __restrict__ num_boxes,
                     float*       __restrict__ out) {
    const int t = (int)threadIdx.x;
    float e = 0.0f;
    if (t < NSLOTS) {
        const int* g = gt_boxes + t * 5;
        const int area = (g[2] - g[0]) * (g[3] - g[1]);
        e = ws_acc[t] / (float)(N_CH * max(area, 1));   // invalid slots: ws==0 -> e==0
    }
    #pragma unroll
    for (int off = 32; off > 0; off >>= 1)
        e += __shfl_down(e, off, 64);

    __shared__ float red[4];
    const int lane = t & 63, wave = t >> 6;
    if (lane == 0) red[wave] = e;
    __syncthreads();
    if (t == 0) {
        float tot = red[0] + red[1] + red[2] + red[3];
        int nb = 0;
        #pragma unroll
        for (int bb = 0; bb < BATCH; ++bb) nb += num_boxes[bb];
        out[0] = tot / (float)nb;
    }
}

extern "C" void kernel_launch(void* const* d_in, const int* in_sizes, int n_in,
                              void* d_out, int out_size, void* d_ws, size_t ws_size,
                              hipStream_t stream) {
    const float* y_fcn    = (const float*)d_in[0];
    const float* im_data  = (const float*)d_in[1];
    // d_in[2] = im_info (unused)
    const int*   gt_boxes = (const int*)d_in[3];
    const int*   num_boxes= (const int*)d_in[4];
    float* out    = (float*)d_out;
    float* ws_acc = (float*)d_ws;

    hipMemsetAsync(ws_acc, 0, NSLOTS * sizeof(float), stream);

    box_err_kernel<<<NSLOTS * PARTS, 64, 0, stream>>>(
        y_fcn, im_data, gt_boxes, num_boxes, ws_acc);

    finalize_kernel<<<1, 256, 0, stream>>>(ws_acc, gt_boxes, num_boxes, out);
}

// Round 4
// 12.583 us; speedup vs baseline: 2.0855x; 2.0855x over previous
//
#include <hip/hip_runtime.h>

#define BATCH 4
#define N_CH 3
#define NUM_CLASSES 20
#define IMG_H 512
#define IMG_W 512
#define MAX_BOXES 50
#define NSLOTS (BATCH * MAX_BOXES)
#define PARTS 16                    // blocks per box slot
#define BLOCK 256
#define TOTAL_BLOCKS (NSLOTS * PARTS)

// Block (slot, part) sums its share of box `slot`: rows r = part, part+16, ...
// Threads cover the flattened (row, 4col-chunk) space with aligned float4
// loads; edge columns are masked. Every block overwrites ws[blockIdx.x]
// (no zero-init, no atomics; poison-safe).
__global__ __launch_bounds__(BLOCK)
void box_err_kernel(const float* __restrict__ y_fcn,
                    const float* __restrict__ im_data,
                    const int*   __restrict__ gt_boxes,
                    const int*   __restrict__ num_boxes,
                    float*       __restrict__ ws_part) {
    const int slot = blockIdx.x / PARTS;
    const int part = blockIdx.x % PARTS;
    const int b    = slot / MAX_BOXES;
    const int box  = slot % MAX_BOXES;
    const int tid  = (int)threadIdx.x;

    const int* g  = gt_boxes + slot * 5;
    const int x1 = g[0], y1 = g[1], x2 = g[2], y2 = g[3], cls = g[4];
    const int bh = y2 - y1;
    const int c0 = x1 & ~3;                    // 16B-aligned chunk start
    const int n4 = (x2 - c0 + 3) >> 2;         // float4 chunks per row

    const int nrows = (part < bh) ? ((bh - part + PARTS - 1) / PARTS) : 0;
    const int vmax  = (box < num_boxes[b]) ? nrows * n4 : 0;

    const int plane = IMG_H * IMG_W;
    const float* im = im_data + (size_t)b * N_CH * plane;
    const float* yf = y_fcn + ((size_t)b * NUM_CLASSES + cls) * (size_t)(N_CH * plane);

    float s = 0.0f;
    for (int v = tid; v < vmax; v += BLOCK) {
        const int rl  = v / n4;                // row index within this part
        const int ic  = v - rl * n4;           // chunk index within row
        const int row = y1 + part + rl * PARTS;
        const int cc  = c0 + (ic << 2);
        const int base = row * IMG_W + cc;     // float index, 16B aligned
        // column masks (only first/last chunk of a row are partial)
        const float m0 = (cc + 0 >= x1 && cc + 0 < x2) ? 1.0f : 0.0f;
        const float m1 = (cc + 1 >= x1 && cc + 1 < x2) ? 1.0f : 0.0f;
        const float m2 = (cc + 2 >= x1 && cc + 2 < x2) ? 1.0f : 0.0f;
        const float m3 = (cc + 3 >= x1 && cc + 3 < x2) ? 1.0f : 0.0f;
        #pragma unroll
        for (int nn = 0; nn < N_CH; ++nn) {
            const float4 a = *(const float4*)(im + nn * plane + base);
            const float4 q = *(const float4*)(yf + nn * plane + base);
            float d;
            d = (a.x - q.x) * m0; s = fmaf(d, d, s);
            d = (a.y - q.y) * m1; s = fmaf(d, d, s);
            d = (a.z - q.z) * m2; s = fmaf(d, d, s);
            d = (a.w - q.w) * m3; s = fmaf(d, d, s);
        }
    }

    #pragma unroll
    for (int off = 32; off > 0; off >>= 1)
        s += __shfl_down(s, off, 64);

    __shared__ float red[BLOCK / 64];
    if ((tid & 63) == 0) red[tid >> 6] = s;
    __syncthreads();
    if (tid == 0)
        ws_part[blockIdx.x] = red[0] + red[1] + red[2] + red[3];
}

// One block: slot t sums its 16 contiguous partials, divides by (3*area),
// masks invalid slots, reduces, divides by sum(num_boxes).
__global__ __launch_bounds__(BLOCK)
void finalize_kernel(const float* __restrict__ ws_part,
                     const int*   __restrict__ gt_boxes,
                     const int*   __restrict__ num_boxes,
                     float*       __restrict__ out) {
    const int t = (int)threadIdx.x;
    float e = 0.0f;
    if (t < NSLOTS) {
        const int b   = t / MAX_BOXES;
        const int box = t % MAX_BOXES;
        if (box < num_boxes[b]) {
            const float4* p = (const float4*)(ws_part + t * PARTS);
            float4 s0 = p[0], s1 = p[1], s2 = p[2], s3 = p[3];
            const float sum = (s0.x + s0.y + s0.z + s0.w)
                            + (s1.x + s1.y + s1.z + s1.w)
                            + (s2.x + s2.y + s2.z + s2.w)
                            + (s3.x + s3.y + s3.z + s3.w);
            const int* g = gt_boxes + t * 5;
            const int area = (g[2] - g[0]) * (g[3] - g[1]);
            e = sum / (float)(N_CH * max(area, 1));
        }
    }
    #pragma unroll
    for (int off = 32; off > 0; off >>= 1)
        e += __shfl_down(e, off, 64);

    __shared__ float red[BLOCK / 64];
    if ((t & 63) == 0) red[t >> 6] = e;
    __syncthreads();
    if (t == 0) {
        int nb = 0;
        #pragma unroll
        for (int bb = 0; bb < BATCH; ++bb) nb += num_boxes[bb];
        out[0] = (red[0] + red[1] + red[2] + red[3]) / (float)nb;
    }
}

extern "C" void kernel_launch(void* const* d_in, const int* in_sizes, int n_in,
                              void* d_out, int out_size, void* d_ws, size_t ws_size,
                              hipStream_t stream) {
    const float* y_fcn     = (const float*)d_in[0];
    const float* im_data   = (const float*)d_in[1];
    // d_in[2] = im_info (unused)
    const int*   gt_boxes  = (const int*)d_in[3];
    const int*   num_boxes = (const int*)d_in[4];
    float* out     = (float*)d_out;
    float* ws_part = (float*)d_ws;         // TOTAL_BLOCKS floats

    box_err_kernel<<<TOTAL_BLOCKS, BLOCK, 0, stream>>>(
        y_fcn, im_data, gt_boxes, num_boxes, ws_part);

    finalize_kernel<<<1, BLOCK, 0, stream>>>(ws_part, gt_boxes, num_boxes, out);
}